// Round 1
// baseline (881.612 us; speedup 1.0000x reference)
//
#include <hip/hip_runtime.h>

#define NN 100000
#define NE 1600000
#define INC 512
#define HID 128
#define OUTC 64
#define BN_EPS 1e-5f

#define SCAN_B 1024
#define NB ((NN + SCAN_B - 1) / SCAN_B)   // 98

// ---------------- CSR build ----------------

__global__ void k_init(int* cnt, float* bnsum, float* bnsumsq) {
    int i = blockIdx.x * blockDim.x + threadIdx.x;
    if (i < NN) cnt[i] = 0;
    if (i < HID) { bnsum[i] = 0.f; bnsumsq[i] = 0.f; }
}

__global__ void k_count(const int* __restrict__ col, int* __restrict__ cnt) {
    int e = blockIdx.x * blockDim.x + threadIdx.x;
    if (e < NE) atomicAdd(&cnt[col[e]], 1);
}

__global__ void k_scanA(const int* __restrict__ cnt, int* __restrict__ rowptr, int* __restrict__ bsum) {
    __shared__ int s[SCAN_B];
    int tid = threadIdx.x;
    int i = blockIdx.x * SCAN_B + tid;
    int v = (i < NN) ? cnt[i] : 0;
    s[tid] = v;
    __syncthreads();
    for (int off = 1; off < SCAN_B; off <<= 1) {
        int t = (tid >= off) ? s[tid - off] : 0;
        __syncthreads();
        s[tid] += t;
        __syncthreads();
    }
    if (i < NN) rowptr[i] = s[tid] - v;     // exclusive within chunk
    if (tid == SCAN_B - 1) bsum[blockIdx.x] = s[tid];
}

__global__ void k_scanB(int* bsum) {
    __shared__ int s[NB];
    int tid = threadIdx.x;
    for (int i = tid; i < NB; i += blockDim.x) s[i] = bsum[i];
    __syncthreads();
    if (tid == 0) {
        int run = 0;
        for (int i = 0; i < NB; ++i) { int t = s[i]; s[i] = run; run += t; }
    }
    __syncthreads();
    for (int i = tid; i < NB; i += blockDim.x) bsum[i] = s[i];
}

__global__ void k_scanC(const int* __restrict__ cnt, int* __restrict__ rowptr, int* __restrict__ pos,
                        float* __restrict__ dinv, const int* __restrict__ bsum) {
    int i = blockIdx.x * SCAN_B + threadIdx.x;
    if (i < NN) {
        int v = rowptr[i] + bsum[blockIdx.x];
        rowptr[i] = v;
        pos[i] = v;
        dinv[i] = rsqrtf((float)(cnt[i] + 1));   // +1 = self-loop
    }
    if (i == 0) rowptr[NN] = NE;
}

__global__ void k_fill(const int* __restrict__ row, const int* __restrict__ col,
                       int* __restrict__ pos, int* __restrict__ csr_row) {
    int e = blockIdx.x * blockDim.x + threadIdx.x;
    if (e < NE) {
        int c = col[e];
        int p = atomicAdd(&pos[c], 1);
        csr_row[p] = row[e];
    }
}

// ---------------- GEMM1: h1[N,128] = x[N,512] @ W1[512,128] ----------------

#define G1_BM 64
#define G1_BK 16

__global__ __launch_bounds__(256) void k_gemm1(const float* __restrict__ x, const float* __restrict__ W1,
                                               float* __restrict__ h1) {
    __shared__ float As[G1_BK][66];
    __shared__ float Bs[G1_BK][HID];
    int tid = threadIdx.x;
    int m0 = blockIdx.x * G1_BM;
    int tx = tid & 31, ty = tid >> 5;   // tx: col quad 0..31, ty: row oct 0..7
    float acc[8][4];
    #pragma unroll
    for (int r = 0; r < 8; ++r)
        #pragma unroll
        for (int c = 0; c < 4; ++c) acc[r][c] = 0.f;

    int lm = tid >> 2;          // 0..63
    int lk = (tid & 3) * 4;     // 0,4,8,12
    int rowi = m0 + lm; if (rowi >= NN) rowi = NN - 1;
    const float* xr = x + (size_t)rowi * INC;

    int bc = (tid & 31) * 4;    // 0..124
    int bk = tid >> 5;          // 0..7

    for (int k0 = 0; k0 < INC; k0 += G1_BK) {
        float4 av = *(const float4*)(xr + k0 + lk);
        As[lk + 0][lm] = av.x; As[lk + 1][lm] = av.y;
        As[lk + 2][lm] = av.z; As[lk + 3][lm] = av.w;
        *(float4*)&Bs[bk][bc]     = *(const float4*)(W1 + (size_t)(k0 + bk) * HID + bc);
        *(float4*)&Bs[bk + 8][bc] = *(const float4*)(W1 + (size_t)(k0 + bk + 8) * HID + bc);
        __syncthreads();
        #pragma unroll
        for (int k = 0; k < G1_BK; ++k) {
            float a[8];
            #pragma unroll
            for (int r = 0; r < 8; ++r) a[r] = As[k][ty * 8 + r];
            float4 b = *(const float4*)&Bs[k][tx * 4];
            #pragma unroll
            for (int r = 0; r < 8; ++r) {
                acc[r][0] = fmaf(a[r], b.x, acc[r][0]);
                acc[r][1] = fmaf(a[r], b.y, acc[r][1]);
                acc[r][2] = fmaf(a[r], b.z, acc[r][2]);
                acc[r][3] = fmaf(a[r], b.w, acc[r][3]);
            }
        }
        __syncthreads();
    }
    #pragma unroll
    for (int r = 0; r < 8; ++r) {
        int m = m0 + ty * 8 + r;
        if (m < NN) {
            *(float4*)(h1 + (size_t)m * HID + tx * 4) =
                make_float4(acc[r][0], acc[r][1], acc[r][2], acc[r][3]);
        }
    }
}

// ---------------- aggregation 1 (128 ch) ----------------

__global__ __launch_bounds__(256) void k_agg1(const float* __restrict__ h1, const float* __restrict__ dinv,
                                              const int* __restrict__ rowptr, const int* __restrict__ csr_row,
                                              const float* __restrict__ b1, float* __restrict__ agg) {
    int node = blockIdx.x * 2 + (threadIdx.x >> 7);
    int c = threadIdx.x & 127;
    float di = dinv[node];
    float acc = di * di * h1[(size_t)node * HID + c];   // self-loop
    int s = rowptr[node], e = rowptr[node + 1];
    for (int j = s; j < e; ++j) {
        int r = csr_row[j];
        acc += di * dinv[r] * h1[(size_t)r * HID + c];
    }
    agg[(size_t)node * HID + c] = acc + b1[c];
}

// ---------------- BN stats ----------------

__global__ __launch_bounds__(256) void k_bnstats(const float* __restrict__ agg,
                                                 float* __restrict__ bnsum, float* __restrict__ bnsumsq) {
    __shared__ float ss[256], sq[256];
    int c = threadIdx.x & 127;
    int half = threadIdx.x >> 7;
    float fs = 0.f, fq = 0.f;
    int rows_per_block = (NN + gridDim.x - 1) / gridDim.x;
    int r0 = blockIdx.x * rows_per_block;
    int r1 = r0 + rows_per_block; if (r1 > NN) r1 = NN;
    for (int r = r0 + half; r < r1; r += 2) {
        float v = agg[(size_t)r * HID + c];
        fs += v; fq += v * v;
    }
    ss[threadIdx.x] = fs; sq[threadIdx.x] = fq;
    __syncthreads();
    if (threadIdx.x < 128) {
        atomicAdd(&bnsum[c], ss[threadIdx.x] + ss[threadIdx.x + 128]);
        atomicAdd(&bnsumsq[c], sq[threadIdx.x] + sq[threadIdx.x + 128]);
    }
}

__global__ void k_bnfinal(const float* __restrict__ bnsum, const float* __restrict__ bnsumsq,
                          const float* __restrict__ gamma, const float* __restrict__ beta,
                          float* __restrict__ bnscale, float* __restrict__ bnshift) {
    int c = threadIdx.x;
    if (c < HID) {
        float mu = bnsum[c] / (float)NN;
        float var = bnsumsq[c] / (float)NN - mu * mu;
        float sc = gamma[c] * rsqrtf(var + BN_EPS);
        bnscale[c] = sc;
        bnshift[c] = beta[c] - mu * sc;
    }
}

// ---------------- GEMM2: h2[N,64] = relu(bn(agg1)) @ W2[128,64], BN+ReLU fused ----------------

__global__ __launch_bounds__(256) void k_gemm2(const float* __restrict__ agg, const float* __restrict__ W2,
                                               const float* __restrict__ bnscale, const float* __restrict__ bnshift,
                                               float* __restrict__ h2) {
    __shared__ float As[32][66];
    __shared__ float Bs[32][OUTC];
    int tid = threadIdx.x;
    int m0 = blockIdx.x * 64;
    int tx = tid & 15, ty = tid >> 4;
    float acc[4][4];
    #pragma unroll
    for (int r = 0; r < 4; ++r)
        #pragma unroll
        for (int c = 0; c < 4; ++c) acc[r][c] = 0.f;

    int am = tid >> 3;          // 0..31
    int ak = (tid & 7) * 4;     // 0..28
    int bk = tid >> 4;          // 0..15
    int bc = (tid & 15) * 4;    // 0..60

    for (int k0 = 0; k0 < HID; k0 += 32) {
        #pragma unroll
        for (int h = 0; h < 2; ++h) {
            int m = am + h * 32;
            int rowi = m0 + m; if (rowi >= NN) rowi = NN - 1;
            float4 v  = *(const float4*)(agg + (size_t)rowi * HID + k0 + ak);
            float4 sc = *(const float4*)(bnscale + k0 + ak);
            float4 sh = *(const float4*)(bnshift + k0 + ak);
            As[ak + 0][m] = fmaxf(fmaf(v.x, sc.x, sh.x), 0.f);
            As[ak + 1][m] = fmaxf(fmaf(v.y, sc.y, sh.y), 0.f);
            As[ak + 2][m] = fmaxf(fmaf(v.z, sc.z, sh.z), 0.f);
            As[ak + 3][m] = fmaxf(fmaf(v.w, sc.w, sh.w), 0.f);
        }
        #pragma unroll
        for (int h = 0; h < 2; ++h) {
            int k = bk + h * 16;
            *(float4*)&Bs[k][bc] = *(const float4*)(W2 + (size_t)(k0 + k) * OUTC + bc);
        }
        __syncthreads();
        #pragma unroll
        for (int k = 0; k < 32; ++k) {
            float a[4];
            #pragma unroll
            for (int r = 0; r < 4; ++r) a[r] = As[k][ty * 4 + r];
            float4 b = *(const float4*)&Bs[k][tx * 4];
            #pragma unroll
            for (int r = 0; r < 4; ++r) {
                acc[r][0] = fmaf(a[r], b.x, acc[r][0]);
                acc[r][1] = fmaf(a[r], b.y, acc[r][1]);
                acc[r][2] = fmaf(a[r], b.z, acc[r][2]);
                acc[r][3] = fmaf(a[r], b.w, acc[r][3]);
            }
        }
        __syncthreads();
    }
    #pragma unroll
    for (int r = 0; r < 4; ++r) {
        int m = m0 + ty * 4 + r;
        if (m < NN) {
            *(float4*)(h2 + (size_t)m * OUTC + tx * 4) =
                make_float4(acc[r][0], acc[r][1], acc[r][2], acc[r][3]);
        }
    }
}

// ---------------- aggregation 2 (64 ch) -> out ----------------

__global__ __launch_bounds__(256) void k_agg2(const float* __restrict__ h2, const float* __restrict__ dinv,
                                              const int* __restrict__ rowptr, const int* __restrict__ csr_row,
                                              const float* __restrict__ b2, float* __restrict__ out) {
    int node = blockIdx.x * 4 + (threadIdx.x >> 6);
    int c = threadIdx.x & 63;
    float di = dinv[node];
    float acc = di * di * h2[(size_t)node * OUTC + c];  // self-loop
    int s = rowptr[node], e = rowptr[node + 1];
    for (int j = s; j < e; ++j) {
        int r = csr_row[j];
        acc += di * dinv[r] * h2[(size_t)r * OUTC + c];
    }
    out[(size_t)node * OUTC + c] = acc + b2[c];
}

// ---------------- launch ----------------

extern "C" void kernel_launch(void* const* d_in, const int* in_sizes, int n_in,
                              void* d_out, int out_size, void* d_ws, size_t ws_size,
                              hipStream_t stream) {
    const float* x     = (const float*)d_in[0];
    const int*   ei    = (const int*)d_in[1];
    const float* W1    = (const float*)d_in[2];
    const float* b1    = (const float*)d_in[3];
    const float* gamma = (const float*)d_in[4];
    const float* beta  = (const float*)d_in[5];
    const float* W2    = (const float*)d_in[6];
    const float* b2    = (const float*)d_in[7];
    const int* row = ei;          // edge_index[0]
    const int* col = ei + NE;     // edge_index[1]
    float* out = (float*)d_out;

    float* h1      = (float*)d_ws;                     // N*128
    float* agg1    = h1 + (size_t)NN * HID;            // N*128
    float* h2      = agg1 + (size_t)NN * HID;          // N*64
    float* dinv    = h2 + (size_t)NN * OUTC;           // N
    float* bnsum   = dinv + NN;                        // 128
    float* bnsumsq = bnsum + HID;                      // 128
    float* bnscale = bnsumsq + HID;                    // 128
    float* bnshift = bnscale + HID;                    // 128
    int*   cnt     = (int*)(bnshift + HID);            // N
    int*   rowptr  = cnt + NN;                         // N+1
    int*   pos     = rowptr + (NN + 1);                // N
    int*   csr_row = pos + NN;                         // E
    int*   bsum    = csr_row + NE;                     // NB

    hipLaunchKernelGGL(k_init,  dim3((NN + 255) / 256), dim3(256), 0, stream, cnt, bnsum, bnsumsq);
    hipLaunchKernelGGL(k_count, dim3((NE + 255) / 256), dim3(256), 0, stream, col, cnt);
    hipLaunchKernelGGL(k_scanA, dim3(NB), dim3(SCAN_B), 0, stream, cnt, rowptr, bsum);
    hipLaunchKernelGGL(k_scanB, dim3(1), dim3(128), 0, stream, bsum);
    hipLaunchKernelGGL(k_scanC, dim3(NB), dim3(SCAN_B), 0, stream, cnt, rowptr, pos, dinv, bsum);
    hipLaunchKernelGGL(k_fill,  dim3((NE + 255) / 256), dim3(256), 0, stream, row, col, pos, csr_row);
    hipLaunchKernelGGL(k_gemm1, dim3((NN + G1_BM - 1) / G1_BM), dim3(256), 0, stream, x, W1, h1);
    hipLaunchKernelGGL(k_agg1,  dim3(NN / 2), dim3(256), 0, stream, h1, dinv, rowptr, csr_row, b1, agg1);
    hipLaunchKernelGGL(k_bnstats, dim3(512), dim3(256), 0, stream, agg1, bnsum, bnsumsq);
    hipLaunchKernelGGL(k_bnfinal, dim3(1), dim3(128), 0, stream, bnsum, bnsumsq, gamma, beta, bnscale, bnshift);
    hipLaunchKernelGGL(k_gemm2, dim3((NN + 63) / 64), dim3(256), 0, stream, agg1, W2, bnscale, bnshift, h2);
    hipLaunchKernelGGL(k_agg2,  dim3(NN / 4), dim3(256), 0, stream, h2, dinv, rowptr, csr_row, b2, out);
}

// Round 2
// 498.324 us; speedup vs baseline: 1.7692x; 1.7692x over previous
//
#include <hip/hip_runtime.h>

#define NN 100000
#define NE 1600000
#define INC 512
#define HID 128
#define OUTC 64
#define BN_EPS 1e-5f

#define SCAN_B 1024
#define NB ((NN + SCAN_B - 1) / SCAN_B)   // 98

typedef __attribute__((ext_vector_type(8))) short short8v;
typedef __attribute__((ext_vector_type(4))) float f32x4;

__device__ __forceinline__ unsigned short f2bf(float f) {
    unsigned u = __float_as_uint(f);
    u += 0x7FFFu + ((u >> 16) & 1u);     // round-to-nearest-even
    return (unsigned short)(u >> 16);
}

// ---------------- CSR build ----------------

__global__ void k_init(int* cnt, float* bnsum, float* bnsumsq) {
    int i = blockIdx.x * blockDim.x + threadIdx.x;
    if (i < NN) cnt[i] = 0;
    if (i < HID) { bnsum[i] = 0.f; bnsumsq[i] = 0.f; }
}

__global__ void k_count(const int* __restrict__ col, int* __restrict__ cnt) {
    int e = blockIdx.x * blockDim.x + threadIdx.x;
    if (e < NE) atomicAdd(&cnt[col[e]], 1);
}

__global__ void k_scanA(const int* __restrict__ cnt, int* __restrict__ rowptr, int* __restrict__ bsum) {
    __shared__ int s[SCAN_B];
    int tid = threadIdx.x;
    int i = blockIdx.x * SCAN_B + tid;
    int v = (i < NN) ? cnt[i] : 0;
    s[tid] = v;
    __syncthreads();
    for (int off = 1; off < SCAN_B; off <<= 1) {
        int t = (tid >= off) ? s[tid - off] : 0;
        __syncthreads();
        s[tid] += t;
        __syncthreads();
    }
    if (i < NN) rowptr[i] = s[tid] - v;     // exclusive within chunk
    if (tid == SCAN_B - 1) bsum[blockIdx.x] = s[tid];
}

__global__ void k_scanB(int* bsum) {
    __shared__ int s[NB];
    int tid = threadIdx.x;
    for (int i = tid; i < NB; i += blockDim.x) s[i] = bsum[i];
    __syncthreads();
    if (tid == 0) {
        int run = 0;
        for (int i = 0; i < NB; ++i) { int t = s[i]; s[i] = run; run += t; }
    }
    __syncthreads();
    for (int i = tid; i < NB; i += blockDim.x) bsum[i] = s[i];
}

// cntpos: in = degree count, out = fill cursor (aliased to save ws)
__global__ void k_scanC(int* cntpos, int* rowptr, float* dinv, const int* __restrict__ bsum) {
    int i = blockIdx.x * SCAN_B + threadIdx.x;
    if (i < NN) {
        int deg = cntpos[i];
        float dv = rsqrtf((float)(deg + 1));   // +1 = self-loop
        int v = rowptr[i] + bsum[blockIdx.x];
        rowptr[i] = v;
        dinv[i] = dv;
        cntpos[i] = v;                          // becomes fill cursor
    }
    if (i == 0) rowptr[NN] = NE;
}

__global__ void k_fill(const int* __restrict__ row, const int* __restrict__ col,
                       const float* __restrict__ dinv, int* __restrict__ pos,
                       int2* __restrict__ csr) {
    int e = blockIdx.x * blockDim.x + threadIdx.x;
    if (e < NE) {
        int r = row[e], c = col[e];
        float w = dinv[r] * dinv[c];
        int p = atomicAdd(&pos[c], 1);
        csr[p] = make_int2(r, __float_as_int(w));
    }
}

// ---------------- W1 -> bf16 transposed [128][512] ----------------

__global__ void k_prepW1(const float* __restrict__ W1, unsigned short* __restrict__ W1T) {
    int i = blockIdx.x * 256 + threadIdx.x;    // 65536 elements
    int k = i >> 7, n = i & 127;
    W1T[(size_t)n * INC + k] = f2bf(W1[i]);
}

// ---------------- GEMM1 (MFMA): h1[N,128] = bf16(x)[N,512] @ bf16(W1)[512,128] ----------------
// block: 64 rows x 128 cols, 4 waves; wave w: all 64 rows x cols [32w,32w+32)

#define G1BK 64
#define APAD 72   // LDS row stride in shorts (144B = 36 dwords -> 2-way bank alias, free)

__global__ __launch_bounds__(256) void k_gemm1m(const float* __restrict__ x,
                                                const unsigned short* __restrict__ W1T,
                                                float* __restrict__ h1) {
    __shared__ unsigned short As[64][APAD];
    __shared__ unsigned short Bs[128][APAD];
    int tid = threadIdx.x;
    int m0 = blockIdx.x * 64;
    int w = tid >> 6;
    int lane = tid & 63;

    f32x4 acc[4][2];
    #pragma unroll
    for (int mr = 0; mr < 4; ++mr)
        #pragma unroll
        for (int cb = 0; cb < 2; ++cb) acc[mr][cb] = (f32x4){0.f, 0.f, 0.f, 0.f};

    // A staging: thread -> row tid>>2, k-seg (tid&3)*16
    int ar = tid >> 2;
    int ak = (tid & 3) * 16;
    int arow = m0 + ar; if (arow >= NN) arow = NN - 1;
    const float* xr = x + (size_t)arow * INC;
    // B staging: thread -> col tid>>1, k-seg (tid&1)*32
    int br = tid >> 1;
    int bk = (tid & 1) * 32;
    const unsigned short* wr = W1T + (size_t)br * INC;

    int frow = lane & 15;
    int fk = (lane >> 4) * 8;

    for (int k0 = 0; k0 < INC; k0 += G1BK) {
        #pragma unroll
        for (int q = 0; q < 4; ++q) {
            float4 v = *(const float4*)(xr + k0 + ak + q * 4);
            *(ushort4*)&As[ar][ak + q * 4] =
                make_ushort4(f2bf(v.x), f2bf(v.y), f2bf(v.z), f2bf(v.w));
        }
        #pragma unroll
        for (int q = 0; q < 4; ++q) {
            *(short8v*)&Bs[br][bk + q * 8] = *(const short8v*)(wr + k0 + bk + q * 8);
        }
        __syncthreads();
        #pragma unroll
        for (int kk = 0; kk < G1BK; kk += 32) {
            short8v a[4], b[2];
            #pragma unroll
            for (int mr = 0; mr < 4; ++mr)
                a[mr] = *(const short8v*)&As[16 * mr + frow][kk + fk];
            #pragma unroll
            for (int cb = 0; cb < 2; ++cb)
                b[cb] = *(const short8v*)&Bs[32 * w + 16 * cb + frow][kk + fk];
            #pragma unroll
            for (int mr = 0; mr < 4; ++mr)
                #pragma unroll
                for (int cb = 0; cb < 2; ++cb)
                    acc[mr][cb] = __builtin_amdgcn_mfma_f32_16x16x32_bf16(a[mr], b[cb], acc[mr][cb], 0, 0, 0);
        }
        __syncthreads();
    }
    // C/D: col = lane&15, row = (lane>>4)*4 + j   [m89-verified]
    int col = lane & 15;
    int r4 = (lane >> 4) * 4;
    #pragma unroll
    for (int mr = 0; mr < 4; ++mr) {
        #pragma unroll
        for (int cb = 0; cb < 2; ++cb) {
            #pragma unroll
            for (int j = 0; j < 4; ++j) {
                int m = m0 + 16 * mr + r4 + j;
                if (m < NN) h1[(size_t)m * HID + 32 * w + 16 * cb + col] = acc[mr][cb][j];
            }
        }
    }
}

// ---------------- aggregation 1 (128 ch): 1 wave/node, float2/lane ----------------

__global__ __launch_bounds__(256) void k_agg1(const float* __restrict__ h1, const float* __restrict__ dinv,
                                              const int* __restrict__ rowptr, const int2* __restrict__ csr,
                                              const float* __restrict__ b1, float* __restrict__ agg) {
    int node = blockIdx.x * 4 + (threadIdx.x >> 6);
    int lane = threadIdx.x & 63;
    const float2* hp = (const float2*)h1;          // 64 float2 per row
    size_t base = (size_t)node * 64 + lane;
    float di = dinv[node];
    float2 hv = hp[base];
    float sx = di * di * hv.x, sy = di * di * hv.y;
    int s = rowptr[node], e = rowptr[node + 1];
    int j = s;
    for (; j + 4 <= e; j += 4) {
        int2 c0 = csr[j], c1 = csr[j + 1], c2 = csr[j + 2], c3 = csr[j + 3];
        float2 v0 = hp[(size_t)c0.x * 64 + lane];
        float2 v1 = hp[(size_t)c1.x * 64 + lane];
        float2 v2 = hp[(size_t)c2.x * 64 + lane];
        float2 v3 = hp[(size_t)c3.x * 64 + lane];
        float w0 = __int_as_float(c0.y), w1 = __int_as_float(c1.y);
        float w2 = __int_as_float(c2.y), w3 = __int_as_float(c3.y);
        sx = fmaf(w0, v0.x, sx); sy = fmaf(w0, v0.y, sy);
        sx = fmaf(w1, v1.x, sx); sy = fmaf(w1, v1.y, sy);
        sx = fmaf(w2, v2.x, sx); sy = fmaf(w2, v2.y, sy);
        sx = fmaf(w3, v3.x, sx); sy = fmaf(w3, v3.y, sy);
    }
    for (; j < e; ++j) {
        int2 c = csr[j];
        float2 v = hp[(size_t)c.x * 64 + lane];
        float w = __int_as_float(c.y);
        sx = fmaf(w, v.x, sx); sy = fmaf(w, v.y, sy);
    }
    float2 bb = ((const float2*)b1)[lane];
    ((float2*)agg)[base] = make_float2(sx + bb.x, sy + bb.y);
}

// ---------------- BN stats ----------------

__global__ __launch_bounds__(256) void k_bnstats(const float* __restrict__ agg,
                                                 float* __restrict__ bnsum, float* __restrict__ bnsumsq) {
    __shared__ float ss[256], sq[256];
    int c = threadIdx.x & 127;
    int half = threadIdx.x >> 7;
    float fs = 0.f, fq = 0.f;
    int rows_per_block = (NN + gridDim.x - 1) / gridDim.x;
    int r0 = blockIdx.x * rows_per_block;
    int r1 = r0 + rows_per_block; if (r1 > NN) r1 = NN;
    for (int r = r0 + half; r < r1; r += 2) {
        float v = agg[(size_t)r * HID + c];
        fs += v; fq += v * v;
    }
    ss[threadIdx.x] = fs; sq[threadIdx.x] = fq;
    __syncthreads();
    if (threadIdx.x < 128) {
        atomicAdd(&bnsum[c], ss[threadIdx.x] + ss[threadIdx.x + 128]);
        atomicAdd(&bnsumsq[c], sq[threadIdx.x] + sq[threadIdx.x + 128]);
    }
}

__global__ void k_bnfinal(const float* __restrict__ bnsum, const float* __restrict__ bnsumsq,
                          const float* __restrict__ gamma, const float* __restrict__ beta,
                          float* __restrict__ bnscale, float* __restrict__ bnshift) {
    int c = threadIdx.x;
    if (c < HID) {
        float mu = bnsum[c] / (float)NN;
        float var = bnsumsq[c] / (float)NN - mu * mu;
        float sc = gamma[c] * rsqrtf(var + BN_EPS);
        bnscale[c] = sc;
        bnshift[c] = beta[c] - mu * sc;
    }
}

// ---------------- GEMM2: h2[N,64] = relu(bn(agg1)) @ W2[128,64], BN+ReLU fused ----------------

__global__ __launch_bounds__(256) void k_gemm2(const float* __restrict__ agg, const float* __restrict__ W2,
                                               const float* __restrict__ bnscale, const float* __restrict__ bnshift,
                                               float* __restrict__ h2) {
    __shared__ float As2[32][66];
    __shared__ float Bs2[32][OUTC];
    int tid = threadIdx.x;
    int m0 = blockIdx.x * 64;
    int tx = tid & 15, ty = tid >> 4;
    float acc[4][4];
    #pragma unroll
    for (int r = 0; r < 4; ++r)
        #pragma unroll
        for (int c = 0; c < 4; ++c) acc[r][c] = 0.f;

    int am = tid >> 3;          // 0..31
    int ak = (tid & 7) * 4;     // 0..28
    int bk = tid >> 4;          // 0..15
    int bc = (tid & 15) * 4;    // 0..60

    for (int k0 = 0; k0 < HID; k0 += 32) {
        #pragma unroll
        for (int h = 0; h < 2; ++h) {
            int m = am + h * 32;
            int rowi = m0 + m; if (rowi >= NN) rowi = NN - 1;
            float4 v  = *(const float4*)(agg + (size_t)rowi * HID + k0 + ak);
            float4 sc = *(const float4*)(bnscale + k0 + ak);
            float4 sh = *(const float4*)(bnshift + k0 + ak);
            As2[ak + 0][m] = fmaxf(fmaf(v.x, sc.x, sh.x), 0.f);
            As2[ak + 1][m] = fmaxf(fmaf(v.y, sc.y, sh.y), 0.f);
            As2[ak + 2][m] = fmaxf(fmaf(v.z, sc.z, sh.z), 0.f);
            As2[ak + 3][m] = fmaxf(fmaf(v.w, sc.w, sh.w), 0.f);
        }
        #pragma unroll
        for (int h = 0; h < 2; ++h) {
            int k = bk + h * 16;
            *(float4*)&Bs2[k][bc] = *(const float4*)(W2 + (size_t)(k0 + k) * OUTC + bc);
        }
        __syncthreads();
        #pragma unroll
        for (int k = 0; k < 32; ++k) {
            float a[4];
            #pragma unroll
            for (int r = 0; r < 4; ++r) a[r] = As2[k][ty * 4 + r];
            float4 b = *(const float4*)&Bs2[k][tx * 4];
            #pragma unroll
            for (int r = 0; r < 4; ++r) {
                acc[r][0] = fmaf(a[r], b.x, acc[r][0]);
                acc[r][1] = fmaf(a[r], b.y, acc[r][1]);
                acc[r][2] = fmaf(a[r], b.z, acc[r][2]);
                acc[r][3] = fmaf(a[r], b.w, acc[r][3]);
            }
        }
        __syncthreads();
    }
    #pragma unroll
    for (int r = 0; r < 4; ++r) {
        int m = m0 + ty * 4 + r;
        if (m < NN) {
            *(float4*)(h2 + (size_t)m * OUTC + tx * 4) =
                make_float4(acc[r][0], acc[r][1], acc[r][2], acc[r][3]);
        }
    }
}

// ---------------- aggregation 2 (64 ch): 1 wave/node, float/lane ----------------

__global__ __launch_bounds__(256) void k_agg2(const float* __restrict__ h2, const float* __restrict__ dinv,
                                              const int* __restrict__ rowptr, const int2* __restrict__ csr,
                                              const float* __restrict__ b2, float* __restrict__ out) {
    int node = blockIdx.x * 4 + (threadIdx.x >> 6);
    int lane = threadIdx.x & 63;
    size_t base = (size_t)node * OUTC + lane;
    float di = dinv[node];
    float acc = di * di * h2[base];
    int s = rowptr[node], e = rowptr[node + 1];
    int j = s;
    for (; j + 4 <= e; j += 4) {
        int2 c0 = csr[j], c1 = csr[j + 1], c2 = csr[j + 2], c3 = csr[j + 3];
        float v0 = h2[(size_t)c0.x * OUTC + lane];
        float v1 = h2[(size_t)c1.x * OUTC + lane];
        float v2 = h2[(size_t)c2.x * OUTC + lane];
        float v3 = h2[(size_t)c3.x * OUTC + lane];
        acc = fmaf(__int_as_float(c0.y), v0, acc);
        acc = fmaf(__int_as_float(c1.y), v1, acc);
        acc = fmaf(__int_as_float(c2.y), v2, acc);
        acc = fmaf(__int_as_float(c3.y), v3, acc);
    }
    for (; j < e; ++j) {
        int2 c = csr[j];
        acc = fmaf(__int_as_float(c.y), h2[(size_t)c.x * OUTC + lane], acc);
    }
    out[base] = acc + b2[lane];
}

// ---------------- launch ----------------

extern "C" void kernel_launch(void* const* d_in, const int* in_sizes, int n_in,
                              void* d_out, int out_size, void* d_ws, size_t ws_size,
                              hipStream_t stream) {
    const float* x     = (const float*)d_in[0];
    const int*   ei    = (const int*)d_in[1];
    const float* W1    = (const float*)d_in[2];
    const float* b1    = (const float*)d_in[3];
    const float* gamma = (const float*)d_in[4];
    const float* beta  = (const float*)d_in[5];
    const float* W2    = (const float*)d_in[6];
    const float* b2    = (const float*)d_in[7];
    const int* row = ei;          // edge_index[0]
    const int* col = ei + NE;     // edge_index[1]
    float* out = (float*)d_out;

    char* wp = (char*)d_ws;
    auto alloc = [&](size_t bytes) -> void* {
        void* p = (void*)wp;
        wp += (bytes + 15) & ~(size_t)15;
        return p;
    };
    float* h1      = (float*)alloc((size_t)NN * HID * 4);
    float* agg1    = (float*)alloc((size_t)NN * HID * 4);
    float* h2      = (float*)alloc((size_t)NN * OUTC * 4);
    float* dinv    = (float*)alloc((size_t)NN * 4);
    float* bnsum   = (float*)alloc(HID * 4);
    float* bnsumsq = (float*)alloc(HID * 4);
    float* bnscale = (float*)alloc(HID * 4);
    float* bnshift = (float*)alloc(HID * 4);
    int*   rowptr  = (int*)alloc((size_t)(NN + 1) * 4);
    int*   cntpos  = (int*)alloc((size_t)NN * 4);
    int*   bsum    = (int*)alloc(NB * 4);
    int2*  csr     = (int2*)alloc((size_t)NE * 8);
    unsigned short* W1T = (unsigned short*)alloc((size_t)HID * INC * 2);

    hipLaunchKernelGGL(k_init,  dim3((NN + 255) / 256), dim3(256), 0, stream, cntpos, bnsum, bnsumsq);
    hipLaunchKernelGGL(k_count, dim3((NE + 255) / 256), dim3(256), 0, stream, col, cntpos);
    hipLaunchKernelGGL(k_scanA, dim3(NB), dim3(SCAN_B), 0, stream, cntpos, rowptr, bsum);
    hipLaunchKernelGGL(k_scanB, dim3(1), dim3(128), 0, stream, bsum);
    hipLaunchKernelGGL(k_scanC, dim3(NB), dim3(SCAN_B), 0, stream, cntpos, rowptr, dinv, bsum);
    hipLaunchKernelGGL(k_fill,  dim3((NE + 255) / 256), dim3(256), 0, stream, row, col, dinv, cntpos, csr);
    hipLaunchKernelGGL(k_prepW1, dim3(256), dim3(256), 0, stream, W1, W1T);
    hipLaunchKernelGGL(k_gemm1m, dim3((NN + 63) / 64), dim3(256), 0, stream, x, W1T, h1);
    hipLaunchKernelGGL(k_agg1,  dim3(NN / 4), dim3(256), 0, stream, h1, dinv, rowptr, csr, b1, agg1);
    hipLaunchKernelGGL(k_bnstats, dim3(512), dim3(256), 0, stream, agg1, bnsum, bnsumsq);
    hipLaunchKernelGGL(k_bnfinal, dim3(1), dim3(128), 0, stream, bnsum, bnsumsq, gamma, beta, bnscale, bnshift);
    hipLaunchKernelGGL(k_gemm2, dim3((NN + 63) / 64), dim3(256), 0, stream, agg1, W2, bnscale, bnshift, h2);
    hipLaunchKernelGGL(k_agg2,  dim3(NN / 4), dim3(256), 0, stream, h2, dinv, rowptr, csr, b2, out);
}

// Round 3
// 434.015 us; speedup vs baseline: 2.0313x; 1.1482x over previous
//
#include <hip/hip_runtime.h>

#define NN 100000
#define NE 1600000
#define INC 512
#define HID 128
#define OUTC 64
#define BN_EPS 1e-5f

#define SCAN_B 1024
#define NB ((NN + SCAN_B - 1) / SCAN_B)   // 98

typedef __attribute__((ext_vector_type(8))) short short8v;
typedef __attribute__((ext_vector_type(4))) float f32x4;

__device__ __forceinline__ unsigned short f2bf(float f) {
    unsigned u = __float_as_uint(f);
    u += 0x7FFFu + ((u >> 16) & 1u);     // round-to-nearest-even
    return (unsigned short)(u >> 16);
}

// ---------------- CSR build ----------------

__global__ void k_init(int* cnt, float* bnsum, float* bnsumsq) {
    int i = blockIdx.x * blockDim.x + threadIdx.x;
    if (i < NN) cnt[i] = 0;
    if (i < HID) { bnsum[i] = 0.f; bnsumsq[i] = 0.f; }
}

__global__ void k_count(const int* __restrict__ col, int* __restrict__ cnt) {
    int e = blockIdx.x * blockDim.x + threadIdx.x;
    if (e < NE) atomicAdd(&cnt[col[e]], 1);
}

__global__ void k_scanA(const int* __restrict__ cnt, int* __restrict__ rowptr, int* __restrict__ bsum) {
    __shared__ int s[SCAN_B];
    int tid = threadIdx.x;
    int i = blockIdx.x * SCAN_B + tid;
    int v = (i < NN) ? cnt[i] : 0;
    s[tid] = v;
    __syncthreads();
    for (int off = 1; off < SCAN_B; off <<= 1) {
        int t = (tid >= off) ? s[tid - off] : 0;
        __syncthreads();
        s[tid] += t;
        __syncthreads();
    }
    if (i < NN) rowptr[i] = s[tid] - v;     // exclusive within chunk
    if (tid == SCAN_B - 1) bsum[blockIdx.x] = s[tid];
}

__global__ void k_scanB(int* bsum) {
    __shared__ int s[NB];
    int tid = threadIdx.x;
    for (int i = tid; i < NB; i += blockDim.x) s[i] = bsum[i];
    __syncthreads();
    if (tid == 0) {
        int run = 0;
        for (int i = 0; i < NB; ++i) { int t = s[i]; s[i] = run; run += t; }
    }
    __syncthreads();
    for (int i = tid; i < NB; i += blockDim.x) bsum[i] = s[i];
}

// cntpos: in = degree count, out = fill cursor (aliased to save ws)
__global__ void k_scanC(int* cntpos, int* rowptr, float* dinv, const int* __restrict__ bsum) {
    int i = blockIdx.x * SCAN_B + threadIdx.x;
    if (i < NN) {
        int deg = cntpos[i];
        float dv = rsqrtf((float)(deg + 1));   // +1 = self-loop
        int v = rowptr[i] + bsum[blockIdx.x];
        rowptr[i] = v;
        dinv[i] = dv;
        cntpos[i] = v;                          // becomes fill cursor
    }
    if (i == 0) rowptr[NN] = NE;
}

__global__ void k_fill(const int* __restrict__ row, const int* __restrict__ col,
                       const float* __restrict__ dinv, int* __restrict__ pos,
                       int2* __restrict__ csr) {
    int e = blockIdx.x * blockDim.x + threadIdx.x;
    if (e < NE) {
        int r = row[e], c = col[e];
        float w = dinv[r] * dinv[c];
        int p = atomicAdd(&pos[c], 1);
        csr[p] = make_int2(r, __float_as_int(w));
    }
}

// ---------------- W1 -> bf16 transposed [128][512] ----------------

__global__ void k_prepW1(const float* __restrict__ W1, unsigned short* __restrict__ W1T) {
    int i = blockIdx.x * 256 + threadIdx.x;    // 65536 elements
    int k = i >> 7, n = i & 127;
    W1T[(size_t)n * INC + k] = f2bf(W1[i]);
}

// ---------------- GEMM1 (MFMA): h1b[N,128](bf16) = bf16(x)[N,512] @ bf16(W1)[512,128] ----------------
// block: 64 rows x 128 cols, 4 waves; wave w: all 64 rows x cols [32w,32w+32)
// MFMA operands SWAPPED (A=W channels, B=x nodes) so each lane owns 4 consecutive
// output channels of one node -> ushort4 (8B) packed bf16 stores.

#define G1BK 64
#define APAD 72   // LDS row stride in shorts (144B -> 2-way bank alias, free)

__global__ __launch_bounds__(256) void k_gemm1m(const float* __restrict__ x,
                                                const unsigned short* __restrict__ W1T,
                                                unsigned short* __restrict__ h1b) {
    __shared__ unsigned short As[64][APAD];
    __shared__ unsigned short Bs[128][APAD];
    int tid = threadIdx.x;
    int m0 = blockIdx.x * 64;
    int w = tid >> 6;
    int lane = tid & 63;

    f32x4 acc[4][2];
    #pragma unroll
    for (int mr = 0; mr < 4; ++mr)
        #pragma unroll
        for (int cb = 0; cb < 2; ++cb) acc[mr][cb] = (f32x4){0.f, 0.f, 0.f, 0.f};

    // A staging: thread -> row tid>>2, k-seg (tid&3)*16
    int ar = tid >> 2;
    int ak = (tid & 3) * 16;
    int arow = m0 + ar; if (arow >= NN) arow = NN - 1;
    const float* xr = x + (size_t)arow * INC;
    // B staging: thread -> col tid>>1, k-seg (tid&1)*32
    int br = tid >> 1;
    int bk = (tid & 1) * 32;
    const unsigned short* wr = W1T + (size_t)br * INC;

    int frow = lane & 15;
    int fk = (lane >> 4) * 8;

    for (int k0 = 0; k0 < INC; k0 += G1BK) {
        #pragma unroll
        for (int q = 0; q < 4; ++q) {
            float4 v = *(const float4*)(xr + k0 + ak + q * 4);
            *(ushort4*)&As[ar][ak + q * 4] =
                make_ushort4(f2bf(v.x), f2bf(v.y), f2bf(v.z), f2bf(v.w));
        }
        #pragma unroll
        for (int q = 0; q < 4; ++q) {
            *(short8v*)&Bs[br][bk + q * 8] = *(const short8v*)(wr + k0 + bk + q * 8);
        }
        __syncthreads();
        #pragma unroll
        for (int kk = 0; kk < G1BK; kk += 32) {
            short8v a[4], b[2];
            #pragma unroll
            for (int mr = 0; mr < 4; ++mr)
                a[mr] = *(const short8v*)&As[16 * mr + frow][kk + fk];   // x nodes (B operand)
            #pragma unroll
            for (int cb = 0; cb < 2; ++cb)
                b[cb] = *(const short8v*)&Bs[32 * w + 16 * cb + frow][kk + fk];  // W channels (A operand)
            #pragma unroll
            for (int mr = 0; mr < 4; ++mr)
                #pragma unroll
                for (int cb = 0; cb < 2; ++cb)
                    acc[mr][cb] = __builtin_amdgcn_mfma_f32_16x16x32_bf16(b[cb], a[mr], acc[mr][cb], 0, 0, 0);
        }
        __syncthreads();
    }
    // D[row=channel][col=node]: node = m0+16mr+(lane&15), channels = 32w+16cb+(lane>>4)*4 + j
    int ncol = lane & 15;
    int r4 = (lane >> 4) * 4;
    #pragma unroll
    for (int mr = 0; mr < 4; ++mr) {
        int node = m0 + 16 * mr + ncol;
        if (node < NN) {
            #pragma unroll
            for (int cb = 0; cb < 2; ++cb) {
                int ch = 32 * w + 16 * cb + r4;
                *(ushort4*)&h1b[(size_t)node * HID + ch] =
                    make_ushort4(f2bf(acc[mr][cb][0]), f2bf(acc[mr][cb][1]),
                                 f2bf(acc[mr][cb][2]), f2bf(acc[mr][cb][3]));
            }
        }
    }
}

// ---------------- aggregation 1 (128 ch bf16): 1 wave/node, packed uint (2ch)/lane ----------------

__global__ __launch_bounds__(256) void k_agg1(const unsigned short* __restrict__ h1b,
                                              const float* __restrict__ dinv,
                                              const int* __restrict__ rowptr, const int2* __restrict__ csr,
                                              const float* __restrict__ b1, float* __restrict__ agg) {
    int node = blockIdx.x * 4 + (threadIdx.x >> 6);
    int lane = threadIdx.x & 63;
    const unsigned* hp = (const unsigned*)h1b;     // 64 uints per row (2 bf16 ch each)
    size_t base = (size_t)node * 64 + lane;
    float di = dinv[node];
    unsigned hv = hp[base];
    float sx = di * di * __uint_as_float(hv << 16);
    float sy = di * di * __uint_as_float(hv & 0xFFFF0000u);
    int s = rowptr[node], e = rowptr[node + 1];
    int j = s;
    for (; j + 4 <= e; j += 4) {
        int2 c0 = csr[j], c1 = csr[j + 1], c2 = csr[j + 2], c3 = csr[j + 3];
        unsigned v0 = hp[(size_t)c0.x * 64 + lane];
        unsigned v1 = hp[(size_t)c1.x * 64 + lane];
        unsigned v2 = hp[(size_t)c2.x * 64 + lane];
        unsigned v3 = hp[(size_t)c3.x * 64 + lane];
        float w0 = __int_as_float(c0.y), w1 = __int_as_float(c1.y);
        float w2 = __int_as_float(c2.y), w3 = __int_as_float(c3.y);
        sx = fmaf(w0, __uint_as_float(v0 << 16), sx); sy = fmaf(w0, __uint_as_float(v0 & 0xFFFF0000u), sy);
        sx = fmaf(w1, __uint_as_float(v1 << 16), sx); sy = fmaf(w1, __uint_as_float(v1 & 0xFFFF0000u), sy);
        sx = fmaf(w2, __uint_as_float(v2 << 16), sx); sy = fmaf(w2, __uint_as_float(v2 & 0xFFFF0000u), sy);
        sx = fmaf(w3, __uint_as_float(v3 << 16), sx); sy = fmaf(w3, __uint_as_float(v3 & 0xFFFF0000u), sy);
    }
    for (; j < e; ++j) {
        int2 c = csr[j];
        unsigned v = hp[(size_t)c.x * 64 + lane];
        float w = __int_as_float(c.y);
        sx = fmaf(w, __uint_as_float(v << 16), sx);
        sy = fmaf(w, __uint_as_float(v & 0xFFFF0000u), sy);
    }
    float2 bb = ((const float2*)b1)[lane];
    ((float2*)agg)[base] = make_float2(sx + bb.x, sy + bb.y);
}

// ---------------- BN stats ----------------

__global__ __launch_bounds__(256) void k_bnstats(const float* __restrict__ agg,
                                                 float* __restrict__ bnsum, float* __restrict__ bnsumsq) {
    __shared__ float ss[256], sq[256];
    int c = threadIdx.x & 127;
    int half = threadIdx.x >> 7;
    float fs = 0.f, fq = 0.f;
    int rows_per_block = (NN + gridDim.x - 1) / gridDim.x;
    int r0 = blockIdx.x * rows_per_block;
    int r1 = r0 + rows_per_block; if (r1 > NN) r1 = NN;
    for (int r = r0 + half; r < r1; r += 2) {
        float v = agg[(size_t)r * HID + c];
        fs += v; fq += v * v;
    }
    ss[threadIdx.x] = fs; sq[threadIdx.x] = fq;
    __syncthreads();
    if (threadIdx.x < 128) {
        atomicAdd(&bnsum[c], ss[threadIdx.x] + ss[threadIdx.x + 128]);
        atomicAdd(&bnsumsq[c], sq[threadIdx.x] + sq[threadIdx.x + 128]);
    }
}

__global__ void k_bnfinal(const float* __restrict__ bnsum, const float* __restrict__ bnsumsq,
                          const float* __restrict__ gamma, const float* __restrict__ beta,
                          float* __restrict__ bnscale, float* __restrict__ bnshift) {
    int c = threadIdx.x;
    if (c < HID) {
        float mu = bnsum[c] / (float)NN;
        float var = bnsumsq[c] / (float)NN - mu * mu;
        float sc = gamma[c] * rsqrtf(var + BN_EPS);
        bnscale[c] = sc;
        bnshift[c] = beta[c] - mu * sc;
    }
}

// ---------------- GEMM2: h2b[N,64](bf16) = relu(bn(agg1)) @ W2[128,64], BN+ReLU fused ----------------

__global__ __launch_bounds__(256) void k_gemm2(const float* __restrict__ agg, const float* __restrict__ W2,
                                               const float* __restrict__ bnscale, const float* __restrict__ bnshift,
                                               unsigned short* __restrict__ h2b) {
    __shared__ float As2[32][66];
    __shared__ float Bs2[32][OUTC];
    int tid = threadIdx.x;
    int m0 = blockIdx.x * 64;
    int tx = tid & 15, ty = tid >> 4;
    float acc[4][4];
    #pragma unroll
    for (int r = 0; r < 4; ++r)
        #pragma unroll
        for (int c = 0; c < 4; ++c) acc[r][c] = 0.f;

    int am = tid >> 3;          // 0..31
    int ak = (tid & 7) * 4;     // 0..28
    int bk = tid >> 4;          // 0..15
    int bc = (tid & 15) * 4;    // 0..60

    for (int k0 = 0; k0 < HID; k0 += 32) {
        #pragma unroll
        for (int h = 0; h < 2; ++h) {
            int m = am + h * 32;
            int rowi = m0 + m; if (rowi >= NN) rowi = NN - 1;
            float4 v  = *(const float4*)(agg + (size_t)rowi * HID + k0 + ak);
            float4 sc = *(const float4*)(bnscale + k0 + ak);
            float4 sh = *(const float4*)(bnshift + k0 + ak);
            As2[ak + 0][m] = fmaxf(fmaf(v.x, sc.x, sh.x), 0.f);
            As2[ak + 1][m] = fmaxf(fmaf(v.y, sc.y, sh.y), 0.f);
            As2[ak + 2][m] = fmaxf(fmaf(v.z, sc.z, sh.z), 0.f);
            As2[ak + 3][m] = fmaxf(fmaf(v.w, sc.w, sh.w), 0.f);
        }
        #pragma unroll
        for (int h = 0; h < 2; ++h) {
            int k = bk + h * 16;
            *(float4*)&Bs2[k][bc] = *(const float4*)(W2 + (size_t)(k0 + k) * OUTC + bc);
        }
        __syncthreads();
        #pragma unroll
        for (int k = 0; k < 32; ++k) {
            float a[4];
            #pragma unroll
            for (int r = 0; r < 4; ++r) a[r] = As2[k][ty * 4 + r];
            float4 b = *(const float4*)&Bs2[k][tx * 4];
            #pragma unroll
            for (int r = 0; r < 4; ++r) {
                acc[r][0] = fmaf(a[r], b.x, acc[r][0]);
                acc[r][1] = fmaf(a[r], b.y, acc[r][1]);
                acc[r][2] = fmaf(a[r], b.z, acc[r][2]);
                acc[r][3] = fmaf(a[r], b.w, acc[r][3]);
            }
        }
        __syncthreads();
    }
    #pragma unroll
    for (int r = 0; r < 4; ++r) {
        int m = m0 + ty * 4 + r;
        if (m < NN) {
            *(ushort4*)(h2b + (size_t)m * OUTC + tx * 4) =
                make_ushort4(f2bf(acc[r][0]), f2bf(acc[r][1]), f2bf(acc[r][2]), f2bf(acc[r][3]));
        }
    }
}

// ---------------- aggregation 2 (64 ch bf16): 1 wave/node, lane-halves alternate edges ----------------

__global__ __launch_bounds__(256) void k_agg2(const unsigned short* __restrict__ h2b,
                                              const float* __restrict__ dinv,
                                              const int* __restrict__ rowptr, const int2* __restrict__ csr,
                                              const float* __restrict__ b2, float* __restrict__ out) {
    int node = blockIdx.x * 4 + (threadIdx.x >> 6);
    int lane = threadIdx.x & 63;
    int l32 = lane & 31;
    const unsigned* hp = (const unsigned*)h2b;     // 32 uints per row (2 bf16 ch each)
    float di = dinv[node];
    float sx = 0.f, sy = 0.f;
    if (lane < 32) {
        unsigned u = hp[(size_t)node * 32 + l32];
        sx = di * di * __uint_as_float(u << 16);
        sy = di * di * __uint_as_float(u & 0xFFFF0000u);
    }
    int s = rowptr[node], e = rowptr[node + 1];
    int j = s + (lane >> 5);
    for (; j + 2 < e; j += 4) {
        int2 c0 = csr[j], c1 = csr[j + 2];
        unsigned v0 = hp[(size_t)c0.x * 32 + l32];
        unsigned v1 = hp[(size_t)c1.x * 32 + l32];
        float w0 = __int_as_float(c0.y), w1 = __int_as_float(c1.y);
        sx = fmaf(w0, __uint_as_float(v0 << 16), sx); sy = fmaf(w0, __uint_as_float(v0 & 0xFFFF0000u), sy);
        sx = fmaf(w1, __uint_as_float(v1 << 16), sx); sy = fmaf(w1, __uint_as_float(v1 & 0xFFFF0000u), sy);
    }
    if (j < e) {
        int2 c = csr[j];
        unsigned v = hp[(size_t)c.x * 32 + l32];
        float w = __int_as_float(c.y);
        sx = fmaf(w, __uint_as_float(v << 16), sx);
        sy = fmaf(w, __uint_as_float(v & 0xFFFF0000u), sy);
    }
    // combine the two lane-halves (each holds partials for the same channel pair)
    sx += __shfl_xor(sx, 32);
    sy += __shfl_xor(sy, 32);
    if (lane < 32) {
        float2 bb = ((const float2*)b2)[l32];
        ((float2*)out)[(size_t)node * 32 + l32] = make_float2(sx + bb.x, sy + bb.y);
    }
}

// ---------------- launch ----------------

extern "C" void kernel_launch(void* const* d_in, const int* in_sizes, int n_in,
                              void* d_out, int out_size, void* d_ws, size_t ws_size,
                              hipStream_t stream) {
    const float* x     = (const float*)d_in[0];
    const int*   ei    = (const int*)d_in[1];
    const float* W1    = (const float*)d_in[2];
    const float* b1    = (const float*)d_in[3];
    const float* gamma = (const float*)d_in[4];
    const float* beta  = (const float*)d_in[5];
    const float* W2    = (const float*)d_in[6];
    const float* b2    = (const float*)d_in[7];
    const int* row = ei;          // edge_index[0]
    const int* col = ei + NE;     // edge_index[1]
    float* out = (float*)d_out;

    char* wp = (char*)d_ws;
    auto alloc = [&](size_t bytes) -> void* {
        void* p = (void*)wp;
        wp += (bytes + 255) & ~(size_t)255;
        return p;
    };
    unsigned short* h1b = (unsigned short*)alloc((size_t)NN * HID * 2);
    float* agg1    = (float*)alloc((size_t)NN * HID * 4);
    unsigned short* h2b = (unsigned short*)alloc((size_t)NN * OUTC * 2);
    float* dinv    = (float*)alloc((size_t)NN * 4);
    float* bnsum   = (float*)alloc(HID * 4);
    float* bnsumsq = (float*)alloc(HID * 4);
    float* bnscale = (float*)alloc(HID * 4);
    float* bnshift = (float*)alloc(HID * 4);
    int*   rowptr  = (int*)alloc((size_t)(NN + 1) * 4);
    int*   cntpos  = (int*)alloc((size_t)NN * 4);
    int*   bsum    = (int*)alloc(NB * 4);
    int2*  csr     = (int2*)alloc((size_t)NE * 8);
    unsigned short* W1T = (unsigned short*)alloc((size_t)HID * INC * 2);

    hipLaunchKernelGGL(k_init,  dim3((NN + 255) / 256), dim3(256), 0, stream, cntpos, bnsum, bnsumsq);
    hipLaunchKernelGGL(k_count, dim3((NE + 255) / 256), dim3(256), 0, stream, col, cntpos);
    hipLaunchKernelGGL(k_scanA, dim3(NB), dim3(SCAN_B), 0, stream, cntpos, rowptr, bsum);
    hipLaunchKernelGGL(k_scanB, dim3(1), dim3(128), 0, stream, bsum);
    hipLaunchKernelGGL(k_scanC, dim3(NB), dim3(SCAN_B), 0, stream, cntpos, rowptr, dinv, bsum);
    hipLaunchKernelGGL(k_fill,  dim3((NE + 255) / 256), dim3(256), 0, stream, row, col, dinv, cntpos, csr);
    hipLaunchKernelGGL(k_prepW1, dim3(256), dim3(256), 0, stream, W1, W1T);
    hipLaunchKernelGGL(k_gemm1m, dim3((NN + 63) / 64), dim3(256), 0, stream, x, W1T, h1b);
    hipLaunchKernelGGL(k_agg1,  dim3(NN / 4), dim3(256), 0, stream, h1b, dinv, rowptr, csr, b1, agg1);
    hipLaunchKernelGGL(k_bnstats, dim3(512), dim3(256), 0, stream, agg1, bnsum, bnsumsq);
    hipLaunchKernelGGL(k_bnfinal, dim3(1), dim3(128), 0, stream, bnsum, bnsumsq, gamma, beta, bnscale, bnshift);
    hipLaunchKernelGGL(k_gemm2, dim3((NN + 63) / 64), dim3(256), 0, stream, agg1, W2, bnscale, bnshift, h2b);
    hipLaunchKernelGGL(k_agg2,  dim3(NN / 4), dim3(256), 0, stream, h2b, dinv, rowptr, csr, b2, out);
}